// Round 1
// baseline (1473.557 us; speedup 1.0000x reference)
//
#include <hip/hip_runtime.h>

#define NZv 1
#define NYv 400
#define NXv 352
#define Bv 4
#define CANVASv (Bv * NZv * NYv * NXv) /* 563200 */
#define EPSF 0.001f
#define VXF 0.2f
#define VYF 0.2f
#define VZF 4.0f
#define XOFFv 0.1f
#define YOFFv -39.9f
#define ZOFFv -1.0f

// ---------------- scatter pass 1: count + coord sums ----------------
__global__ void k_scatter1(const float4* __restrict__ feat, const int4* __restrict__ coors,
                           int* __restrict__ vidx, float* __restrict__ counts,
                           float* __restrict__ sumc, int n)
{
    int i = blockIdx.x * blockDim.x + threadIdx.x;
    if (i >= n) return;
    int4 c = coors[i];
    int v = ((c.x * NZv + c.y) * NYv + c.z) * NXv + c.w;
    vidx[i] = v;
    float4 f = feat[i];
    atomicAdd(&counts[v], 1.0f);
    atomicAdd(&sumc[3 * v + 0], f.x);
    atomicAdd(&sumc[3 * v + 1], f.y);
    atomicAdd(&sumc[3 * v + 2], f.z);
}

// ---------------- scatter pass 2: mean-dist sums ----------------
__global__ void k_scatter2(const float4* __restrict__ feat, const int* __restrict__ vidx,
                           const float* __restrict__ counts, const float* __restrict__ sumc,
                           float* __restrict__ spd, int n)
{
    int i = blockIdx.x * blockDim.x + threadIdx.x;
    if (i >= n) return;
    int v = vidx[i];
    float safe = fmaxf(counts[v], 1.0f);
    float inv = 1.0f / safe;
    float4 f = feat[i];
    float dx = f.x - sumc[3 * v + 0] * inv;
    float dy = f.y - sumc[3 * v + 1] * inv;
    float dz = f.z - sumc[3 * v + 2] * inv;
    atomicAdd(&spd[v], sqrtf(dx * dx + dy * dy + dz * dz));
}

// ---------------- build 13-dim input features, transposed [13][npad] ----------------
__global__ void k_prex(const float4* __restrict__ feat, const int4* __restrict__ coors,
                       const int* __restrict__ vidx, const float* __restrict__ counts,
                       const float* __restrict__ sumc, const float* __restrict__ spd,
                       float* __restrict__ xT, float* __restrict__ fsp, int n, int npad)
{
    int i = blockIdx.x * blockDim.x + threadIdx.x;
    if (i >= n) return;
    float4 f = feat[i];
    int4 c = coors[i];
    int v = vidx[i];
    float safe = fmaxf(counts[v], 1.0f);
    float inv = 1.0f / safe;
    float mx = sumc[3 * v + 0] * inv;
    float my = sumc[3 * v + 1] * inv;
    float mz = sumc[3 * v + 2] * inv;
    float density = safe / 0.16f;
    float mdist = spd[v] * inv;
    float vals[13];
    vals[0] = f.x; vals[1] = f.y; vals[2] = f.z; vals[3] = f.w;
    vals[4] = density; vals[5] = mdist;
    vals[6] = f.x - mx; vals[7] = f.y - my; vals[8] = f.z - mz;
    vals[9]  = f.x - ((float)c.w * VXF + XOFFv);
    vals[10] = f.y - ((float)c.z * VYF + YOFFv);
    vals[11] = f.z - ((float)c.y * VZF + ZOFFv);
    vals[12] = sqrtf(f.x * f.x + f.y * f.y + f.z * f.z);
#pragma unroll
    for (int k = 0; k < 13; ++k) xT[k * npad + i] = vals[k];
    fsp[2 * i + 0] = density;
    fsp[2 * i + 1] = mdist;
}

// ---------------- GEMM0: [64 pts/block] x (13x64) ----------------
__global__ __launch_bounds__(256) void k_gemm0(const float* __restrict__ xT,
                                               const float* __restrict__ W0,
                                               float* __restrict__ y0, int npad)
{
    __shared__ __align__(16) float sW[13 * 64];
    __shared__ __align__(16) float sx[13][68];
    int t = threadIdx.x;
    int base = blockIdx.x * 64;
    for (int idx = t; idx < 13 * 64; idx += 256) sW[idx] = W0[idx];
    for (int idx = t; idx < 13 * 64; idx += 256) {
        int k = idx >> 6, p = idx & 63;
        sx[k][p] = xT[k * npad + base + p];
    }
    __syncthreads();
    int tc = t & 15, tp = t >> 4;
    float acc[4][4];
#pragma unroll
    for (int a = 0; a < 4; ++a)
#pragma unroll
        for (int b = 0; b < 4; ++b) acc[a][b] = 0.f;
#pragma unroll
    for (int k = 0; k < 13; ++k) {
        float4 xv = *reinterpret_cast<const float4*>(&sx[k][4 * tp]);
        float4 wv = *reinterpret_cast<const float4*>(&sW[k * 64 + 4 * tc]);
        float xs[4] = {xv.x, xv.y, xv.z, xv.w};
        float ws4[4] = {wv.x, wv.y, wv.z, wv.w};
#pragma unroll
        for (int a = 0; a < 4; ++a)
#pragma unroll
            for (int b = 0; b < 4; ++b) acc[a][b] = fmaf(xs[a], ws4[b], acc[a][b]);
    }
#pragma unroll
    for (int pp = 0; pp < 4; ++pp) {
        int i = base + 4 * tp + pp;
        float4 o = make_float4(acc[pp][0], acc[pp][1], acc[pp][2], acc[pp][3]);
        *reinterpret_cast<float4*>(&y0[i * 64 + 4 * tc]) = o;
    }
}

// ---------------- per-channel sum / sumsq (double atomics) ----------------
__global__ void k_stats(const float* __restrict__ y, double* __restrict__ s, int total, int C)
{
    int tid = blockIdx.x * blockDim.x + threadIdx.x;
    int stride = gridDim.x * blockDim.x; // multiple of C
    int c = tid & (C - 1);
    double sum = 0.0, sq = 0.0;
    for (int idx = tid; idx < total; idx += stride) {
        float v = y[idx];
        sum += v;
        sq += (double)v * (double)v;
    }
    atomicAdd(&s[c], sum);
    atomicAdd(&s[C + c], sq);
}

__global__ void k_fin(const double* __restrict__ s, const float* __restrict__ g,
                      const float* __restrict__ b, float* __restrict__ sc,
                      float* __restrict__ sh, int n, int C)
{
    int c = threadIdx.x;
    if (c >= C) return;
    double mean = s[c] / (double)n;
    double var = s[C + c] / (double)n - mean * mean;
    float scale = g[c] / sqrtf((float)var + EPSF);
    sc[c] = scale;
    sh[c] = b[c] - (float)mean * scale;
}

// ---------------- apply BN+ReLU to y0 (in place) + segment-max ----------------
__global__ void k_bnmax(float* __restrict__ y0, const int* __restrict__ vidx,
                        const float* __restrict__ sc, const float* __restrict__ sh,
                        unsigned int* __restrict__ vmax, int total)
{
    int idx = blockIdx.x * blockDim.x + threadIdx.x;
    if (idx >= total) return;
    int i = idx >> 6, c = idx & 63;
    float p = fmaxf(fmaf(y0[idx], sc[c], sh[c]), 0.0f);
    y0[idx] = p;
    atomicMax(&vmax[vidx[i] * 64 + c], __float_as_uint(p));
}

// ---------------- GEMM1: x1=[p0|vmax[v]] (128) @ W1 (128x128) -> y1 ----------------
__global__ __launch_bounds__(256) void k_gemm1(const float* __restrict__ p0,
                                               const float* __restrict__ vmaxf,
                                               const int* __restrict__ vidx,
                                               const float* __restrict__ W1,
                                               float* __restrict__ y1, int n, int ntiles)
{
    __shared__ __align__(16) float sW[128 * 128];
    __shared__ __align__(16) float sx[128][20];
    int t = threadIdx.x;
    for (int idx = t; idx < 128 * 128; idx += 256) sW[idx] = W1[idx];
    int tc = t & 31, tp = t >> 5;
    for (int tile = blockIdx.x; tile < ntiles; tile += gridDim.x) {
        __syncthreads();
        int base = tile * 16;
#pragma unroll
        for (int r = 0; r < 8; ++r) {
            int idx = r * 256 + t;
            int p = idx >> 7, k = idx & 127;
            int i = base + p;
            if (i >= n) i = n - 1;
            float val = (k < 64) ? p0[i * 64 + k] : vmaxf[vidx[i] * 64 + (k - 64)];
            sx[k][p] = val;
        }
        __syncthreads();
        float acc[8];
#pragma unroll
        for (int j = 0; j < 8; ++j) acc[j] = 0.f;
#pragma unroll 8
        for (int k = 0; k < 128; ++k) {
            float2 xv = *reinterpret_cast<const float2*>(&sx[k][2 * tp]);
            float4 wv = *reinterpret_cast<const float4*>(&sW[k * 128 + 4 * tc]);
            acc[0] = fmaf(xv.x, wv.x, acc[0]);
            acc[1] = fmaf(xv.x, wv.y, acc[1]);
            acc[2] = fmaf(xv.x, wv.z, acc[2]);
            acc[3] = fmaf(xv.x, wv.w, acc[3]);
            acc[4] = fmaf(xv.y, wv.x, acc[4]);
            acc[5] = fmaf(xv.y, wv.y, acc[5]);
            acc[6] = fmaf(xv.y, wv.z, acc[6]);
            acc[7] = fmaf(xv.y, wv.w, acc[7]);
        }
#pragma unroll
        for (int pp = 0; pp < 2; ++pp) {
            int i = base + 2 * tp + pp;
            if (i < n) {
                float4 o = make_float4(acc[4 * pp + 0], acc[4 * pp + 1], acc[4 * pp + 2], acc[4 * pp + 3]);
                *reinterpret_cast<float4*>(&y1[i * 128 + 4 * tc]) = o;
            }
        }
    }
}

// ---------------- GEMM2: x2=[bnrelu(y1)|fsp] (130) @ Ws + bs, ReLU, in-place ----------------
__global__ __launch_bounds__(256) void k_gemm2(const float* y1, const float* __restrict__ fsp,
                                               const float* __restrict__ Wsp,
                                               const float* __restrict__ bsp,
                                               const float* __restrict__ sc,
                                               const float* __restrict__ sh,
                                               float* outp, int n, int ntiles)
{
    __shared__ __align__(16) float sW[130 * 128];
    __shared__ __align__(16) float sx[130][20];
    __shared__ float ssc[128], ssh[128], sbs[128];
    int t = threadIdx.x;
    for (int idx = t; idx < 130 * 128; idx += 256) sW[idx] = Wsp[idx];
    if (t < 128) { ssc[t] = sc[t]; ssh[t] = sh[t]; sbs[t] = bsp[t]; }
    int tc = t & 31, tp = t >> 5;
    for (int tile = blockIdx.x; tile < ntiles; tile += gridDim.x) {
        __syncthreads();
        int base = tile * 16;
#pragma unroll
        for (int r = 0; r < 8; ++r) {
            int idx = r * 256 + t;
            int p = idx >> 7, k = idx & 127;
            int i = base + p;
            if (i >= n) i = n - 1;
            float val = fmaxf(fmaf(y1[i * 128 + k], ssc[k], ssh[k]), 0.0f);
            sx[k][p] = val;
        }
        if (t < 16) {
            int i = base + t;
            if (i >= n) i = n - 1;
            sx[128][t] = fsp[2 * i + 0];
            sx[129][t] = fsp[2 * i + 1];
        }
        __syncthreads();
        float acc[8];
#pragma unroll
        for (int j = 0; j < 8; ++j) acc[j] = 0.f;
#pragma unroll 8
        for (int k = 0; k < 130; ++k) {
            float2 xv = *reinterpret_cast<const float2*>(&sx[k][2 * tp]);
            float4 wv = *reinterpret_cast<const float4*>(&sW[k * 128 + 4 * tc]);
            acc[0] = fmaf(xv.x, wv.x, acc[0]);
            acc[1] = fmaf(xv.x, wv.y, acc[1]);
            acc[2] = fmaf(xv.x, wv.z, acc[2]);
            acc[3] = fmaf(xv.x, wv.w, acc[3]);
            acc[4] = fmaf(xv.y, wv.x, acc[4]);
            acc[5] = fmaf(xv.y, wv.y, acc[5]);
            acc[6] = fmaf(xv.y, wv.z, acc[6]);
            acc[7] = fmaf(xv.y, wv.w, acc[7]);
        }
#pragma unroll
        for (int pp = 0; pp < 2; ++pp) {
            int i = base + 2 * tp + pp;
            if (i < n) {
                float4 o;
                o.x = fmaxf(acc[4 * pp + 0] + sbs[4 * tc + 0], 0.f);
                o.y = fmaxf(acc[4 * pp + 1] + sbs[4 * tc + 1], 0.f);
                o.z = fmaxf(acc[4 * pp + 2] + sbs[4 * tc + 2], 0.f);
                o.w = fmaxf(acc[4 * pp + 3] + sbs[4 * tc + 3], 0.f);
                *reinterpret_cast<float4*>(&outp[i * 128 + 4 * tc]) = o;
            }
        }
    }
}

extern "C" void kernel_launch(void* const* d_in, const int* in_sizes, int n_in,
                              void* d_out, int out_size, void* d_ws, size_t ws_size,
                              hipStream_t stream)
{
    const float* feat = (const float*)d_in[0];
    const int*   coor = (const int*)d_in[1];
    const float* W0   = (const float*)d_in[2];
    const float* g0   = (const float*)d_in[3];
    const float* b0   = (const float*)d_in[4];
    const float* W1   = (const float*)d_in[5];
    const float* g1   = (const float*)d_in[6];
    const float* b1   = (const float*)d_in[7];
    const float* Wsp  = (const float*)d_in[8];
    const float* bsp  = (const float*)d_in[9];
    float* outp = (float*)d_out;

    int n = in_sizes[0] / 4;
    int npad = ((n + 63) / 64) * 64;

    char* ws = (char*)d_ws;
    size_t off = 0;
    int*    vidx   = (int*)(ws + off);    off += (size_t)npad * 4;
    float*  counts = (float*)(ws + off);  off += (size_t)CANVASv * 4;
    float*  sumc   = (float*)(ws + off);  off += (size_t)CANVASv * 12;
    float*  spd    = (float*)(ws + off);  off += (size_t)CANVASv * 4;
    float*  fsp    = (float*)(ws + off);  off += (size_t)n * 8;
    float*  xT     = (float*)(ws + off);  off += (size_t)npad * 13 * 4;
    float*  y0     = (float*)(ws + off);  off += (size_t)npad * 64 * 4;
    float*  vmax   = (float*)(ws + off);  off += (size_t)CANVASv * 64 * 4;
    double* st0    = (double*)(ws + off); off += 128 * 8;
    double* st1    = (double*)(ws + off); off += 256 * 8;
    float*  sc0    = (float*)(ws + off);  off += 64 * 4;
    float*  sh0    = (float*)(ws + off);  off += 64 * 4;
    float*  sc1    = (float*)(ws + off);  off += 128 * 4;
    float*  sh1    = (float*)(ws + off);  off += 128 * 4;
    if (off > ws_size) return; // insufficient workspace -> fail loudly at validation

    // zero accumulators (counts+sumc+spd contiguous; stats contiguous)
    hipMemsetAsync(counts, 0, (size_t)CANVASv * 4 * 5, stream);
    hipMemsetAsync(vmax, 0, (size_t)CANVASv * 64 * 4, stream);
    hipMemsetAsync(st0, 0, (128 + 256) * 8, stream);

    int blocksN = (n + 255) / 256;
    k_scatter1<<<blocksN, 256, 0, stream>>>((const float4*)feat, (const int4*)coor, vidx, counts, sumc, n);
    k_scatter2<<<blocksN, 256, 0, stream>>>((const float4*)feat, vidx, counts, sumc, spd, n);
    k_prex<<<blocksN, 256, 0, stream>>>((const float4*)feat, (const int4*)coor, vidx, counts, sumc, spd, xT, fsp, n, npad);

    int ntiles0 = (n + 63) / 64;
    k_gemm0<<<ntiles0, 256, 0, stream>>>(xT, W0, y0, npad);
    k_stats<<<512, 256, 0, stream>>>(y0, st0, n * 64, 64);
    k_fin<<<1, 64, 0, stream>>>(st0, g0, b0, sc0, sh0, n, 64);
    k_bnmax<<<(n * 64 + 255) / 256, 256, 0, stream>>>(y0, vidx, sc0, sh0, (unsigned int*)vmax, n * 64);

    int ntiles1 = (n + 15) / 16;
    k_gemm1<<<512, 256, 0, stream>>>(y0, vmax, vidx, W1, outp, n, ntiles1);
    k_stats<<<512, 256, 0, stream>>>(outp, st1, n * 128, 128);
    k_fin<<<1, 128, 0, stream>>>(st1, g1, b1, sc1, sh1, n, 128);
    k_gemm2<<<512, 256, 0, stream>>>(outp, fsp, Wsp, bsp, sc1, sh1, outp, n, ntiles1);
}